// Round 19
// baseline (164.208 us; speedup 1.0000x reference)
//
#include <hip/hip_runtime.h>
#include <hip/hip_bf16.h>

#define NB 16
#define QL 1024
#define DLEN 4096
#define HD 128

#define NIT (QL / 16)          // 64 q-tile intervals of 16 rows
#define NSLICE 256             // 16-k slices per batch (kc*8 + w)

typedef __attribute__((ext_vector_type(8))) short short8;
typedef __attribute__((ext_vector_type(4))) float f32x4;

__device__ __forceinline__ short bf16_of(float x) {
  union { __hip_bfloat16 h; short s; } u;
  u.h = __float2bfloat16(x);
  return u.s;
}
__device__ __forceinline__ short8 cvt8(float4 a, float4 b) {
  short8 r;
  r[0] = bf16_of(a.x); r[1] = bf16_of(a.y); r[2] = bf16_of(a.z); r[3] = bf16_of(a.w);
  r[4] = bf16_of(b.x); r[5] = bf16_of(b.y); r[6] = bf16_of(b.z); r[7] = bf16_of(b.w);
  return r;
}

// Pre-pass: Q fp32 -> bf16 (4.2 MB), once; stays L2-hot (262 KB/batch/XCD).
__global__ __launch_bounds__(256) void cvt_q(const float* __restrict__ in,
                                             short8* __restrict__ outw) {
  const size_t i = (size_t)blockIdx.x * 256 + threadIdx.x;
  const float* p = in + i * 8;
  outw[i] = cvt8(*(const float4*)p, *(const float4*)(p + 4));
}

// Round 19: HIDE THE LDS CONSUME FROM THE COMPILER. Mechanism found for the
// R10-R15 ~88us invariant: any C-level read of LDS written by global_load_lds
// makes the compiler insert its own conservative s_waitcnt vmcnt(~0) before
// the read (it cannot prove which outstanding stages alias) -> the pipeline
// drained EVERY interval in every round; my counted waits were theater.
// Fix: the sim LDS read is an inline-asm ds_read_b128 (opaque -> no compiler
// wait); I own the full wait chain: pinned issue skeleton LOADBQ -> SB ->
// STAGE -> SB -> counted vmcnt -> SB -> asm ds_read -> lgkmcnt(0) -> SB.
// Structure: wave-private (ZERO barriers), wave = (b, 16-k slice), 8 waves x
// 512 blocks = 2 blocks/CU -> ~16 waves/CU (2x R15's TLP). Per 16-q interval:
// 4 pinned reg Q-loads (bf16, L2-hot) + ONE gload_lds (1KB sim panel, 3-deep
// ring, 3KB/wave). Doc A-frags + mask fixed in regs. No-max softmax: scores
// ~N(0,1); masked -> exp underflows to exact 0, identical to ref.
__global__ __launch_bounds__(512, 4) void atten_cross(
    const __hip_bfloat16* __restrict__ qbf, const float* __restrict__ doc,
    const int* __restrict__ dmask, const float* __restrict__ sim,
    float2* __restrict__ ws) {
  const int flat = blockIdx.x;
  const int b = flat & 15;        // flat%8 == b%8 -> batch pinned to one XCD
  const int kc = flat >> 4;       // 0..31: 128-k group; wave owns 16 of it
  const int tid = threadIdx.x;
  const int w = tid >> 6;         // wave 0..7
  const int lane = tid & 63;
  const int grp = lane >> 4;
  const int li = lane & 15;
  const int k0 = kc * 128 + w * 16;
  const int slice = kc * 8 + w;   // 0..255

  __shared__ char lds[8 * 3 * 1024];   // per-wave 3-deep 1KB sim ring
  char* ring = lds + w * 3072;
  const unsigned ring32 = (unsigned)(uintptr_t)ring;  // LDS byte offset

  constexpr float scale = 0.088388347648318447f;  // 1/sqrt(128)

  // ---- fixed per-wave state: doc A-frags + mask ----
  const float* dsrc = doc + ((size_t)b * DLEN + k0 + li) * HD + grp * 8;
  short8 afr[4];
#pragma unroll
  for (int cc = 0; cc < 4; ++cc) {
    const float* p = dsrc + cc * 32;
    afr[cc] = cvt8(*(const float4*)p, *(const float4*)(p + 4));
  }
  int mm[4];
  {
    const int4 mk = *(const int4*)(dmask + (size_t)b * DLEN + k0 + grp * 4);
    mm[0] = mk.x; mm[1] = mk.y; mm[2] = mk.z; mm[3] = mk.w;
  }

  // ---- stage addressing: panel [16 q rows][64 B] ----
  const int srow = lane >> 2;                   // dest q-row
  const char* ssrc = (const char*)sim + ((size_t)b * QL + srow) * (DLEN * 4) +
                     (size_t)k0 * 4 + (lane & 3) * 16;
  char* sdst = ring + lane * 16;

#define STAGE(it, buf)                                                         \
  __builtin_amdgcn_global_load_lds(                                            \
      (const __attribute__((address_space(1))) void*)(ssrc + (size_t)(it) *    \
                                                      (16 * DLEN * 4)),        \
      (__attribute__((address_space(3))) void*)(sdst + (buf) * 1024), 16, 0, 0);

  // ---- Q B-frag source (bf16): row it*16 + li, dims grp*8 + cc*32 ----
  const __hip_bfloat16* qsrc = qbf + ((size_t)b * QL + li) * HD + grp * 8;

#define LOADBQ(it, dst)                                                        \
  {                                                                            \
    const __hip_bfloat16* qp_ = qsrc + (size_t)(it) * (16 * HD);               \
    _Pragma("unroll") for (int cc = 0; cc < 4; ++cc)                           \
      dst[cc] = *(const short8*)(qp_ + cc * 32);                               \
    asm volatile("" : "+v"(dst[0]), "+v"(dst[1]), "+v"(dst[2]), "+v"(dst[3])); \
  }

  const unsigned rdoff = (unsigned)(li * 64 + grp * 16);

#define CONSUME(it, bq)                                                        \
  {                                                                            \
    f32x4 sv;                                                                  \
    const unsigned a_ = ring32 + ((it) % 3) * 1024 + rdoff;                    \
    asm volatile("ds_read_b128 %0, %1" : "=v"(sv) : "v"(a_));                  \
    asm volatile("s_waitcnt lgkmcnt(0)" ::: "memory");                         \
    __builtin_amdgcn_sched_barrier(0);                                         \
    f32x4 acc = {0.f, 0.f, 0.f, 0.f};                                          \
    acc = __builtin_amdgcn_mfma_f32_16x16x32_bf16(afr[0], bq[0], acc, 0, 0, 0);\
    acc = __builtin_amdgcn_mfma_f32_16x16x32_bf16(afr[1], bq[1], acc, 0, 0, 0);\
    acc = __builtin_amdgcn_mfma_f32_16x16x32_bf16(afr[2], bq[2], acc, 0, 0, 0);\
    acc = __builtin_amdgcn_mfma_f32_16x16x32_bf16(afr[3], bq[3], acc, 0, 0, 0);\
    float l = 0.f, nn = 0.f;                                                   \
    _Pragma("unroll") for (int r = 0; r < 4; ++r) {                            \
      float e = __expf(acc[r] * scale);                                        \
      e = mm[r] ? e : 0.f; /* == exp(-9999) == 0 */                            \
      l += e;                                                                  \
      nn = fmaf(e, sv[r], nn);                                                 \
    }                                                                          \
    l += __shfl_xor(l, 16, 64); l += __shfl_xor(l, 32, 64);                    \
    nn += __shfl_xor(nn, 16, 64); nn += __shfl_xor(nn, 32, 64);                \
    if (lane < 16)                                                             \
      ws[((size_t)slice * NB + b) * QL + (it) * 16 + li] = make_float2(l, nn); \
    asm volatile("" ::: "memory");                                             \
  }

  short8 bqA[4], bqB[4];

  // prologue: issue order LOADBQ(0), STAGE(0), STAGE(1)
  LOADBQ(0, bqA);
  __builtin_amdgcn_sched_barrier(0);
  STAGE(0, 0);
  STAGE(1, 1);
  __builtin_amdgcn_sched_barrier(0);

#pragma unroll 1
  for (int p = 0; p < NIT / 2; ++p) {
    const int itE = 2 * p, itO = 2 * p + 1;
    // ---- even: consume bqA(itE) ----
    {
      const int bl = itE + 1;                                  // always < NIT
      LOADBQ(bl, bqB);
      __builtin_amdgcn_sched_barrier(0);
      const int st = (itE + 2 < NIT) ? itE + 2 : NIT - 1;      // tail: dead dup
      STAGE(st, (itE + 2) % 3);
      __builtin_amdgcn_sched_barrier(0);
      // newer than {stage(itE), loadbq(itE)}: st(itE+1)=1 [+store(itE-1)=1]
      // + lb(itE+1)=4 + st(itE+2)=1  ->  6 at p==0, 7 after
      if (p == 0) asm volatile("s_waitcnt vmcnt(6)" ::: "memory");
      else        asm volatile("s_waitcnt vmcnt(7)" ::: "memory");
      __builtin_amdgcn_sched_barrier(0);
      CONSUME(itE, bqA);
    }
    // ---- odd: consume bqB(itO) ----
    {
      const int bl = (itO + 1 < NIT) ? itO + 1 : NIT - 1;      // tail: dead dup
      LOADBQ(bl, bqA);
      __builtin_amdgcn_sched_barrier(0);
      const int st = (itO + 2 < NIT) ? itO + 2 : NIT - 1;
      STAGE(st, (itO + 2) % 3);
      __builtin_amdgcn_sched_barrier(0);
      // newer than {stage(itO), loadbq(itO)}: st(itO+1)+store(itE)+lb+st = 7
      asm volatile("s_waitcnt vmcnt(7)" ::: "memory");
      __builtin_amdgcn_sched_barrier(0);
      CONSUME(itO, bqB);
    }
  }
#undef STAGE
#undef LOADBQ
#undef CONSUME
}

// Finish: per (b,q) sum the 256 slice partials, v=n/l, sum over q -> out[b].
// 256 blocks x 256 threads, coalesced; one atomicAdd per block.
__global__ __launch_bounds__(256) void finish(const float2* __restrict__ ws,
                                              float* __restrict__ out) {
  const int b = blockIdx.x;
  const int qg = blockIdx.y;
  const int t = threadIdx.x;
  const int q = qg * 64 + (t & 63);
  const int sg = t >> 6;  // wave id = slice group (64 slices each)

  float l = 0.f, n = 0.f;
#pragma unroll 8
  for (int s = sg * 64; s < sg * 64 + 64; ++s) {
    const float2 v = ws[((size_t)s * NB + b) * QL + q];
    l += v.x;
    n += v.y;
  }
  __shared__ float rl[4][64], rn[4][64];
  rl[sg][t & 63] = l;
  rn[sg][t & 63] = n;
  __syncthreads();
  if (t < 64) {
    const float lt = rl[0][t] + rl[1][t] + rl[2][t] + rl[3][t];
    const float nt = rn[0][t] + rn[1][t] + rn[2][t] + rn[3][t];
    float v = nt / lt;
#pragma unroll
    for (int m = 32; m >= 1; m >>= 1) v += __shfl_xor(v, m, 64);
    if (t == 0) atomicAdd(out + b, v);
  }
}

extern "C" void kernel_launch(void* const* d_in, const int* in_sizes, int n_in,
                              void* d_out, int out_size, void* d_ws, size_t ws_size,
                              hipStream_t stream) {
  const float* qin = (const float*)d_in[0];
  // d_in[1] = query_mask: unused by the reference
  const float* doc = (const float*)d_in[2];
  const int* dmask = (const int*)d_in[3];
  const float* sim = (const float*)d_in[4];
  float* out = (float*)d_out;

  // ws layout: [0, 33.6 MB) = (l,n) partials (256*16*1024 float2);
  //            [40 MB, +4.2 MB) = Q bf16
  float2* ws = (float2*)d_ws;
  short8* qbf = (short8*)((char*)d_ws + (40u << 20));

  hipMemsetAsync(out, 0, (size_t)out_size * sizeof(float), stream);

  const size_t q_elems = (size_t)NB * QL * HD;  // 2.1M floats
  cvt_q<<<q_elems / (8 * 256), 256, 0, stream>>>(qin, (short8*)qbf);

  dim3 grid(NB * 32);  // 512 blocks: flat = kc*16 + b (2 blocks/CU)
  atten_cross<<<grid, 512, 0, stream>>>((const __hip_bfloat16*)qbf, doc,
                                        dmask, sim, ws);
  finish<<<dim3(NB, 16), 256, 0, stream>>>(ws, out);
}

// Round 20
// 161.352 us; speedup vs baseline: 1.0177x; 1.0177x over previous
//
#include <hip/hip_runtime.h>
#include <hip/hip_bf16.h>

#define NB 16
#define QL 1024
#define DLEN 4096
#define HD 128

#define QS 32                  // q rows per block
#define KI 128                 // k per interval
#define NIT (DLEN / KI)        // 32 intervals
#define SIMPAN (QS * KI * 4)   // 16 KB sim panel
#define NPAN 4                 // 4-deep ring -> single barrier/interval safe

typedef __attribute__((ext_vector_type(8))) short short8;
typedef __attribute__((ext_vector_type(4))) float f32x4;
typedef union { f32x4 f; short8 s; } du;

__device__ __forceinline__ short bf16_of(float x) {
  union { __hip_bfloat16 h; short s; } u;
  u.h = __float2bfloat16(x);
  return u.s;
}
__device__ __forceinline__ short8 cvt8(float4 a, float4 b) {
  short8 r;
  r[0] = bf16_of(a.x); r[1] = bf16_of(a.y); r[2] = bf16_of(a.z); r[3] = bf16_of(a.w);
  r[4] = bf16_of(b.x); r[5] = bf16_of(b.y); r[6] = bf16_of(b.z); r[7] = bf16_of(b.w);
  return r;
}

// fp32 -> bf16 pre-pass (used for Q 4.2 MB and doc 16.8 MB).
__global__ __launch_bounds__(256) void cvt_bf16(const float* __restrict__ in,
                                                short8* __restrict__ outw) {
  const size_t i = (size_t)blockIdx.x * 256 + threadIdx.x;
  const float* p = in + i * 8;
  outw[i] = cvt8(*(const float4*)p, *(const float4*)(p + 4));
}

// doc_mask -> packed bitwords: word[b*128 + i] bit j = mask[b][i*32+j]. 8 KB.
__global__ __launch_bounds__(256) void build_mask(const int* __restrict__ dmask,
                                                  unsigned* __restrict__ mw) {
  const int wi = blockIdx.x * 256 + threadIdx.x;
  if (wi >= NB * 128) return;
  const int b = wi >> 7, i = wi & 127;
  unsigned word = 0;
#pragma unroll
  for (int j = 0; j < 32; ++j)
    if (dmask[(size_t)b * DLEN + i * 32 + j]) word |= (1u << j);
  mw[wi] = word;
}

// Round 20: Q-HELD, K-STREAMED. All R12-R19 walked sim with 16KB row stride
// (64B-1KB granules) -> sim stream stuck ~3 TB/s. Here block=(b, 32-q strip)
// streams k: each of its 32 sim rows is read FULLY SEQUENTIALLY across the 32
// intervals (m13 shape). Q frags: regs, loaded once. l,n accumulate in regs
// across all k -> NO ws partials, NO finish kernel. Per interval: sim panel
// (16KB) via 2 gload_lds/wave into 4-deep ring (4-deep => single raw barrier
// per interval is overwrite-safe); doc (bf16, L2-hot 1MB/batch) via inline-asm
// global_load_dwordx4 (opaque: cannot be sunk/serialized) into dbuf regs;
// mask via wave-uniform s_load bitwords (off the vmcnt path). Exact
// vmcnt(12/10) BEFORE the barrier: own stage(it) complete -> barrier -> all
// waves' stage(it) complete (m201 discipline). Sim LDS XOR-swizzled
// ((row&15)<<4) via pre-swizzled global src -> ~4-way on ds_read_b128.
// No-max softmax: scores ~N(0,1); masked -> exp underflows to exact 0 (=ref).
__global__ __launch_bounds__(512, 4) void atten_cross(
    const __hip_bfloat16* __restrict__ qbf, const __hip_bfloat16* __restrict__ docb,
    const unsigned* __restrict__ mwords, const float* __restrict__ sim,
    float* __restrict__ out) {
  const int flat = blockIdx.x;
  const int b = flat & 15;        // flat%8 == b%8 -> batch pinned to one XCD
  const int qs = flat >> 4;       // 0..31: 32-row q strip
  const int tid = threadIdx.x;
  const int w = tid >> 6;         // 8 waves = 2 qh x 4 ks
  const int lane = tid & 63;
  const int grp = lane >> 4;
  const int li = lane & 15;
  const int qh = w & 1;           // q half (16 rows)
  const int ks = w >> 1;          // 32-k sub-slice of each interval

  __shared__ char simbuf[NPAN * SIMPAN];   // 64 KB
  __shared__ float redl[8][16], redn[8][16];

  constexpr float scale = 0.088388347648318447f;  // 1/sqrt(128)

  // ---- Q fragments (fixed): row qs*32 + qh*16 + li, dims grp*8 + cc*32 ----
  const __hip_bfloat16* gq =
      qbf + ((size_t)b * QL + qs * QS + qh * 16 + li) * HD + grp * 8;
  short8 bq[4];
#pragma unroll
  for (int cc = 0; cc < 4; ++cc) bq[cc] = *(const short8*)(gq + cc * 32);

  // ---- doc pointer (bytes): row ks*32 + li (+ it*128 rows), dim grp*8 ----
  const char* docptr = (const char*)docb +
      (((size_t)b * DLEN + ks * 32 + li) * HD + grp * 8) * 2;

  // ---- mask words: wave-uniform, word index b*128 + it*4 + ks ----
  const unsigned* mwp = mwords + b * 128 + ks;

  // ---- stage addressing: panel [32 rows][512 B]; op j covers 2 rows ----
  const char* ssrc[2];
  int sdd[2];
#pragma unroll
  for (int j = 0; j < 2; ++j) {
    const int dd = (w * 2 + j) * 1024 + lane * 16;
    const int row = dd >> 9, col = dd & 511;
    ssrc[j] = (const char*)sim + ((size_t)b * QL + qs * QS + row) * (DLEN * 4) +
              (col ^ ((row & 15) << 4));
    sdd[j] = dd;
  }

#define STAGE(it, pan)                                                         \
  {                                                                            \
    _Pragma("unroll") for (int j = 0; j < 2; ++j)                              \
      __builtin_amdgcn_global_load_lds(                                        \
          (const __attribute__((address_space(1))) void*)(ssrc[j] +            \
                                                          (size_t)(it) * 512), \
          (__attribute__((address_space(3))) void*)(simbuf + (pan)*SIMPAN +    \
                                                    sdd[j]), 16, 0, 0);        \
    __builtin_amdgcn_sched_barrier(0);                                         \
  }

#define LOADDOC(it, D)                                                         \
  {                                                                            \
    const char* p0_ = docptr + (size_t)(it) * (KI * HD * 2);                   \
    const char* p1_ = p0_ + 16 * HD * 2;                                       \
    asm volatile("global_load_dwordx4 %0, %1, off"            : "=v"(D[0].f) : "v"(p0_)); \
    asm volatile("global_load_dwordx4 %0, %1, off offset:64"  : "=v"(D[1].f) : "v"(p0_)); \
    asm volatile("global_load_dwordx4 %0, %1, off offset:128" : "=v"(D[2].f) : "v"(p0_)); \
    asm volatile("global_load_dwordx4 %0, %1, off offset:192" : "=v"(D[3].f) : "v"(p0_)); \
    asm volatile("global_load_dwordx4 %0, %1, off"            : "=v"(D[4].f) : "v"(p1_)); \
    asm volatile("global_load_dwordx4 %0, %1, off offset:64"  : "=v"(D[5].f) : "v"(p1_)); \
    asm volatile("global_load_dwordx4 %0, %1, off offset:128" : "=v"(D[6].f) : "v"(p1_)); \
    asm volatile("global_load_dwordx4 %0, %1, off offset:192" : "=v"(D[7].f) : "v"(p1_)); \
    __builtin_amdgcn_sched_barrier(0);                                         \
  }

  float l = 0.f, n = 0.f;
  const int prow = qh * 16 + li;
  const int psw = (prow & 15) << 4;

#define CONSUME(it, D, mw)                                                     \
  {                                                                            \
    const char* sp = simbuf + ((it) % NPAN) * SIMPAN;                          \
    _Pragma("unroll") for (int kt = 0; kt < 2; ++kt) {                         \
      f32x4 acc = {0.f, 0.f, 0.f, 0.f};                                        \
      acc = __builtin_amdgcn_mfma_f32_16x16x32_bf16(D[kt*4+0].s, bq[0], acc, 0, 0, 0); \
      acc = __builtin_amdgcn_mfma_f32_16x16x32_bf16(D[kt*4+1].s, bq[1], acc, 0, 0, 0); \
      acc = __builtin_amdgcn_mfma_f32_16x16x32_bf16(D[kt*4+2].s, bq[2], acc, 0, 0, 0); \
      acc = __builtin_amdgcn_mfma_f32_16x16x32_bf16(D[kt*4+3].s, bq[3], acc, 0, 0, 0); \
      const f32x4 sv = *(const f32x4*)(sp + prow * 512 +                       \
          ((ks * 128 + kt * 64 + grp * 16) ^ psw));                            \
      _Pragma("unroll") for (int r = 0; r < 4; ++r) {                          \
        float e = __expf(acc[r] * scale);                                      \
        e = ((mw >> (kt * 16 + grp * 4 + r)) & 1u) ? e : 0.f; /* ==exp(-9999) */ \
        l += e;                                                                \
        n = fmaf(e, sv[r], n);                                                 \
      }                                                                        \
    }                                                                          \
  }

  du dA[8], dB[8];
  unsigned mwA, mwB;

  // prologue: STAGE(0), DOC(0), STAGE(1)
  STAGE(0, 0);
  LOADDOC(0, dA);
  mwA = mwp[0];
  STAGE(1, 1);

#pragma unroll 1
  for (int p = 0; p < NIT / 2; ++p) {
    const int itE = 2 * p, itO = 2 * p + 1;
    {  // even: consume(itE) with dA
      const int st = (itE + 2 < NIT) ? itE + 2 : NIT - 1;   // tail: dead dup
      STAGE(st, (itE + 2) % NPAN);
      LOADDOC(itO, dB);
      mwB = mwp[itO * 4];
      // own stage(itE)+doc(itE) complete: newer = stage(itE+2)[2]+doc(itO)[8]
      // (+stage(1)[2] extra at p==0)
      if (p == 0) asm volatile("s_waitcnt vmcnt(12)" ::: "memory");
      else        asm volatile("s_waitcnt vmcnt(10)" ::: "memory");
      __builtin_amdgcn_s_barrier();       // -> ALL waves' stage(itE) complete
      asm volatile("" ::: "memory");
      __builtin_amdgcn_sched_barrier(0);
      CONSUME(itE, dA, mwA);
    }
    {  // odd: consume(itO) with dB
      const int st = (itO + 2 < NIT) ? itO + 2 : NIT - 1;
      const int dl = (itO + 1 < NIT) ? itO + 1 : NIT - 1;
      STAGE(st, (itO + 2) % NPAN);
      LOADDOC(dl, dA);
      mwA = mwp[dl * 4];
      asm volatile("s_waitcnt vmcnt(10)" ::: "memory");
      __builtin_amdgcn_s_barrier();
      asm volatile("" ::: "memory");
      __builtin_amdgcn_sched_barrier(0);
      CONSUME(itO, dB, mwB);
    }
  }
#undef STAGE
#undef LOADDOC
#undef CONSUME

  // ---- final reduction (once per block): l,n over grp -> per-wave per-q ----
  l += __shfl_xor(l, 16, 64); l += __shfl_xor(l, 32, 64);
  n += __shfl_xor(n, 16, 64); n += __shfl_xor(n, 32, 64);
  if (lane < 16) { redl[w][li] = l; redn[w][li] = n; }
  __syncthreads();   // also drains the dup tail stages

  if (tid < 32) {    // q = (tid>>4)*16 + (tid&15); combine the 4 ks waves
    const int q_h = tid >> 4, q_l = tid & 15;
    float lt = 0.f, nt = 0.f;
#pragma unroll
    for (int k = 0; k < 4; ++k) {
      lt += redl[k * 2 + q_h][q_l];
      nt += redn[k * 2 + q_h][q_l];
    }
    float v = nt / lt;
#pragma unroll
    for (int m = 16; m >= 1; m >>= 1) v += __shfl_xor(v, m, 64);
    if (tid == 0) atomicAdd(out + b, v);
  }
}

extern "C" void kernel_launch(void* const* d_in, const int* in_sizes, int n_in,
                              void* d_out, int out_size, void* d_ws, size_t ws_size,
                              hipStream_t stream) {
  const float* qin = (const float*)d_in[0];
  // d_in[1] = query_mask: unused by the reference
  const float* doc = (const float*)d_in[2];
  const int* dmask = (const int*)d_in[3];
  const float* sim = (const float*)d_in[4];
  float* out = (float*)d_out;

  // ws: [0,4.2MB) Q bf16; [8MB,+16.8MB) doc bf16; [32MB,+8KB) mask words
  short8* qbf = (short8*)d_ws;
  short8* docb = (short8*)((char*)d_ws + (8u << 20));
  unsigned* mwords = (unsigned*)((char*)d_ws + (32u << 20));

  hipMemsetAsync(out, 0, (size_t)out_size * sizeof(float), stream);

  const size_t q_elems = (size_t)NB * QL * HD;     // 2.1M floats
  const size_t d_elems = (size_t)NB * DLEN * HD;   // 8.4M floats
  cvt_bf16<<<q_elems / (8 * 256), 256, 0, stream>>>(qin, qbf);
  cvt_bf16<<<d_elems / (8 * 256), 256, 0, stream>>>(doc, docb);
  build_mask<<<(NB * 128 + 255) / 256, 256, 0, stream>>>(dmask, mwords);

  dim3 grid(NB * 32);  // 512 blocks: flat = qs*16 + b (2 blocks/CU)
  atten_cross<<<grid, 512, 0, stream>>>((const __hip_bfloat16*)qbf,
                                        (const __hip_bfloat16*)docb,
                                        mwords, sim, out);
}

// Round 21
// 91.545 us; speedup vs baseline: 1.7937x; 1.7625x over previous
//
#include <hip/hip_runtime.h>
#include <hip/hip_bf16.h>

#define NB 16
#define QL 1024
#define DLEN 4096
#define HD 128

#define NSL 128                  // k slices of 32 (one per wave)
#define NIT (QL / 16)            // 64 q-tile intervals per wave
#define WLDS (3 * 6144)          // per-wave LDS: 3 bufs x (4KB q + 2KB sim)

typedef __attribute__((ext_vector_type(8))) short short8;
typedef __attribute__((ext_vector_type(4))) float f32x4;

__device__ __forceinline__ short bf16_of(float x) {
  union { __hip_bfloat16 h; short s; } u;
  u.h = __float2bfloat16(x);
  return u.s;
}

__device__ __forceinline__ short8 cvt8(float4 a, float4 b) {
  short8 r;
  r[0] = bf16_of(a.x); r[1] = bf16_of(a.y); r[2] = bf16_of(a.z); r[3] = bf16_of(a.w);
  r[4] = bf16_of(b.x); r[5] = bf16_of(b.y); r[6] = bf16_of(b.z); r[7] = bf16_of(b.w);
  return r;
}

// Pre-pass: Q fp32 -> bf16 (4.2 MB), once.
__global__ __launch_bounds__(256) void cvt_q(const float* __restrict__ in,
                                             short8* __restrict__ outw) {
  const size_t i = (size_t)blockIdx.x * 256 + threadIdx.x;
  const float* p = in + i * 8;
  outw[i] = cvt8(*(const float4*)p, *(const float4*)(p + 4));
}

// FINAL (round 21) = round-15 best-known kernel (93.8 us) + exact vmcnt.
// Wave-private pipeline, ZERO barriers: wave = (b, 32-k slice), doc A-frags +
// mask in registers; each wave stages its own sim(2KB)+Qbf16(4KB) panels into
// a PRIVATE 3-deep LDS ring (18KB/wave, 144KB/block) via global_load_lds.
// Counted vmcnt: at consume(it), ops newer than stage(it) are stage(it+1)[6]
// + store(it-1)[1 when it>=1] -> 6 / 7 / 7 (round-15 used 8 steady-state: one
// op loose = latent race on the last sim stage op; fixed here).
// Consume phase all-LDS. Panels XOR-swizzled ((row&7)<<4) via pre-swizzled
// global source, linear LDS dst. No-max softmax: scores ~N(0,1); masked ->
// exp underflows to exact 0, identical to ref's exp(-9999).
// Post-R20 verdict: 9 structural families (R12-R20) all land 88-95us main;
// deeper-concurrency attacks regressed under pre-committed falsifiers.
// This is the best verified configuration.
__global__ __launch_bounds__(512) void atten_cross(
    const __hip_bfloat16* __restrict__ qbf, const float* __restrict__ doc,
    const int* __restrict__ dmask, const float* __restrict__ sim,
    float2* __restrict__ ws) {
  const int flat = blockIdx.x;
  const int b = flat & 15;        // flat%8 == b%8 -> batch pinned to one XCD
  const int g = flat >> 4;        // 0..15: slice group
  const int tid = threadIdx.x;
  const int w = tid >> 6;         // wave 0..7
  const int lane = tid & 63;
  const int grp = lane >> 4;
  const int li = lane & 15;
  const int slice = g * 8 + w;    // 0..127
  const int k0 = slice * 32;

  __shared__ char lds[8 * WLDS];  // 147456 B; wave-private 18KB regions
  const int wbase = w * WLDS;

  // ---- prologue: doc A-frags + mask into registers (fixed for this wave) ----
  const float* dsrc = doc + ((size_t)b * DLEN + k0 + li) * HD + grp * 8;
  short8 afr[2][4];
#pragma unroll
  for (int kt = 0; kt < 2; ++kt)
#pragma unroll
    for (int cc = 0; cc < 4; ++cc) {
      const float* p = dsrc + (size_t)kt * 16 * HD + cc * 32;
      afr[kt][cc] = cvt8(*(const float4*)p, *(const float4*)(p + 4));
    }
  const int* mp = dmask + (size_t)b * DLEN + k0 + grp * 4;
  const int4 mk0 = *(const int4*)(mp);
  const int4 mk1 = *(const int4*)(mp + 16);

  // ---- loop-invariant stage addressing ----
  // Q panel [16 rows][256B], sim panel [16 rows][128B];
  // LDS[row][x] = g[row][x ^ ((row&7)<<4)] via pre-swizzled global source.
  const char* gq = (const char*)qbf + ((size_t)b * QL) * (HD * 2);
  const char* gsim = (const char*)sim + ((size_t)b * QL) * (DLEN * 4) + (size_t)k0 * 4;
  const char* qsrcj[4];
#pragma unroll
  for (int j = 0; j < 4; ++j) {
    const int row = j * 4 + (lane >> 4), x = (lane & 15) * 16;
    qsrcj[j] = gq + (size_t)row * 256 + (x ^ ((row & 7) << 4));
  }
  const char* ssrcj[2];
#pragma unroll
  for (int j = 0; j < 2; ++j) {
    const int row = j * 8 + (lane >> 3), x = (lane & 7) * 16;
    ssrcj[j] = gsim + (size_t)row * (DLEN * 4) + (x ^ ((row & 7) << 4));
  }

#define STAGE(it, pan)                                                         \
  {                                                                            \
    const size_t qo = (size_t)(it) * (16 * HD * 2);                            \
    const size_t so = (size_t)(it) * (16 * DLEN * 4);                          \
    _Pragma("unroll") for (int j = 0; j < 4; ++j)                              \
      __builtin_amdgcn_global_load_lds(                                        \
          (const __attribute__((address_space(1))) void*)(qsrcj[j] + qo),      \
          (__attribute__((address_space(3))) void*)(lds + wbase + (pan)*6144 + j*1024 + lane*16), \
          16, 0, 0);                                                           \
    _Pragma("unroll") for (int j = 0; j < 2; ++j)                              \
      __builtin_amdgcn_global_load_lds(                                        \
          (const __attribute__((address_space(1))) void*)(ssrcj[j] + so),      \
          (__attribute__((address_space(3))) void*)(lds + wbase + (pan)*6144 + 4096 + j*1024 + lane*16), \
          16, 0, 0);                                                           \
  }

  constexpr float scale = 0.088388347648318447f;  // 1/sqrt(128)
  const int qxor = (li & 7) << 4;
  const int mm0[4] = {mk0.x, mk0.y, mk0.z, mk0.w};
  const int mm1[4] = {mk1.x, mk1.y, mk1.z, mk1.w};

  STAGE(0, 0);
  STAGE(1, 1);

#pragma unroll 1
  for (int it = 0; it < NIT; ++it) {
    // exact wave-private counted wait for stage(it):
    // newer ops = stage(it+1)[6] + store(it-1)[1 when it>=1] -> 6 / 7 / 7
    if (it == 0) asm volatile("s_waitcnt vmcnt(6)" ::: "memory");
    else         asm volatile("s_waitcnt vmcnt(7)" ::: "memory");
    __builtin_amdgcn_sched_barrier(0);

    {  // stage it+2 into buf (it+2)%3 == (it-1)%3, consumed by THIS wave last
       // interval -- private, so no barrier needed before overwrite.
      const int nx = (it + 2 < NIT) ? it + 2 : NIT - 1;  // tail: dead reload
      STAGE(nx, (it + 2) % 3);
    }

    const char* qp = lds + wbase + (it % 3) * 6144;
    const char* sp = qp + 4096;

    short8 bfrag[4];
#pragma unroll
    for (int cc = 0; cc < 4; ++cc)
      bfrag[cc] = *(const short8*)(qp + li * 256 + ((grp * 16 + cc * 64) ^ qxor));

    float l = 0.f, nn = 0.f;
#pragma unroll
    for (int kt = 0; kt < 2; ++kt) {
      f32x4 acc = {0.f, 0.f, 0.f, 0.f};
      acc = __builtin_amdgcn_mfma_f32_16x16x32_bf16(afr[kt][0], bfrag[0], acc, 0, 0, 0);
      acc = __builtin_amdgcn_mfma_f32_16x16x32_bf16(afr[kt][1], bfrag[1], acc, 0, 0, 0);
      acc = __builtin_amdgcn_mfma_f32_16x16x32_bf16(afr[kt][2], bfrag[2], acc, 0, 0, 0);
      acc = __builtin_amdgcn_mfma_f32_16x16x32_bf16(afr[kt][3], bfrag[3], acc, 0, 0, 0);
      const f32x4 sv = *(const f32x4*)(sp + li * 128 + ((kt * 64 + grp * 16) ^ qxor));
#pragma unroll
      for (int r = 0; r < 4; ++r) {
        float e = __expf(acc[r] * scale);
        e = (kt ? mm1[r] : mm0[r]) ? e : 0.f;  // == exp(-9999) == 0
        l += e;
        nn = fmaf(e, sv[r], nn);
      }
    }

    // reduce over grp groups -> lane li holds (l,n) for q = it*16 + li
    l += __shfl_xor(l, 16, 64); l += __shfl_xor(l, 32, 64);
    nn += __shfl_xor(nn, 16, 64); nn += __shfl_xor(nn, 32, 64);
    if (lane < 16)
      ws[((size_t)slice * NB + b) * QL + it * 16 + li] = make_float2(l, nn);
  }
#undef STAGE
}

// Finish: 256 blocks (16 b x 16 q-groups of 64) x 256 threads; 64 KB
// coalesced per block; one atomicAdd per block (out memset to 0 first).
__global__ __launch_bounds__(256) void finish(const float2* __restrict__ ws,
                                              float* __restrict__ out) {
  const int b = blockIdx.x;
  const int qg = blockIdx.y;
  const int t = threadIdx.x;
  const int q = qg * 64 + (t & 63);
  const int sg = t >> 6;  // wave id = slice group (32 slices each)

  float l = 0.f, n = 0.f;
#pragma unroll 8
  for (int s = sg * 32; s < sg * 32 + 32; ++s) {
    const float2 v = ws[((size_t)s * NB + b) * QL + q];
    l += v.x;
    n += v.y;
  }
  __shared__ float rl[4][64], rn[4][64];
  rl[sg][t & 63] = l;
  rn[sg][t & 63] = n;
  __syncthreads();
  if (t < 64) {
    const float lt = rl[0][t] + rl[1][t] + rl[2][t] + rl[3][t];
    const float nt = rn[0][t] + rn[1][t] + rn[2][t] + rn[3][t];
    float v = nt / lt;
#pragma unroll
    for (int m = 32; m >= 1; m >>= 1) v += __shfl_xor(v, m, 64);
    if (t == 0) atomicAdd(out + b, v);
  }
}

extern "C" void kernel_launch(void* const* d_in, const int* in_sizes, int n_in,
                              void* d_out, int out_size, void* d_ws, size_t ws_size,
                              hipStream_t stream) {
  const float* qin = (const float*)d_in[0];
  // d_in[1] = query_mask: unused by the reference
  const float* doc = (const float*)d_in[2];
  const int* dmask = (const int*)d_in[3];
  const float* sim = (const float*)d_in[4];
  float* out = (float*)d_out;

  // ws layout: [0, 16.78 MB) = (l,n) partials; [16.78 MB, +4.2 MB) = Q bf16
  float2* ws = (float2*)d_ws;
  short8* qbf = (short8*)((char*)d_ws + (size_t)128 * NB * QL * 8);

  hipMemsetAsync(out, 0, (size_t)out_size * sizeof(float), stream);

  const size_t q_elems = (size_t)NB * QL * HD;  // 2.1M floats
  cvt_q<<<q_elems / (8 * 256), 256, 0, stream>>>(qin, qbf);

  dim3 grid(NB * 16);  // 256 blocks: flat = g*16 + b -> exactly 1 per CU
  atten_cross<<<grid, 512, 0, stream>>>((const __hip_bfloat16*)qbf, doc,
                                        dmask, sim, ws);
  finish<<<dim3(NB, 16), 256, 0, stream>>>(ws, out);
}